// Round 5
// baseline (80.937 us; speedup 1.0000x reference)
//
#include <hip/hip_runtime.h>

// AbstractRelu (DeepPoly ReLU relaxation), elementwise over N=16M fp32.
// Outputs concatenated: [x_out | low_out | high_out], each N floats.
// Memory-bound: 192 MiB in + 192 MiB out, touched once.
// Exact-map, TWO ADJACENT float4 per thread: wave covers contiguous 8KB per
// stream (best DRAM page locality), half the waves of round-3, still minimal
// per-wave state. Nontemporal everywhere (no reuse, footprint > L3).

#define EPS 1e-7f

typedef float f32x4 __attribute__((ext_vector_type(4)));

__device__ __forceinline__ void relax_one(float X, float L, float H,
                                          float& xo, float& lo, float& ho) {
    xo = fmaxf(X, 0.0f);

    const bool crossing = (L < 0.0f) & (H > 0.0f);
    const bool dead = (H <= 0.0f);

    // Match reference exactly: denom = crossing ? (H-L) : 1.0
    // ub_slope uses denom+EPS, ub_int uses bare denom.
    const float denom = crossing ? (H - L) : 1.0f;
    const float ub_slope = H / (denom + EPS);
    const float ub_int = -(L * H) / denom;
    const float high_cross = ub_slope * H + ub_int;
    // LAMDA = 0 -> low_cross = 0

    ho = crossing ? high_cross : (dead ? 0.0f : H);
    lo = crossing ? 0.0f : (dead ? 0.0f : L);
}

__device__ __forceinline__ void relax_vec(const f32x4& xv, const f32x4& lv,
                                          const f32x4& hv, f32x4& xr,
                                          f32x4& lr, f32x4& hr) {
    float a, b, c;
    relax_one(xv.x, lv.x, hv.x, a, b, c); xr.x = a; lr.x = b; hr.x = c;
    relax_one(xv.y, lv.y, hv.y, a, b, c); xr.y = a; lr.y = b; hr.y = c;
    relax_one(xv.z, lv.z, hv.z, a, b, c); xr.z = a; lr.z = b; hr.z = c;
    relax_one(xv.w, lv.w, hv.w, a, b, c); xr.w = a; lr.w = b; hr.w = c;
}

__global__ void __launch_bounds__(256)
abstract_relu_kernel(const f32x4* __restrict__ x,
                     const f32x4* __restrict__ low,
                     const f32x4* __restrict__ high,
                     f32x4* __restrict__ x_out,
                     f32x4* __restrict__ low_out,
                     f32x4* __restrict__ high_out) {
    // Each thread handles float4 elements 2t and 2t+1 (adjacent).
    const int t = blockIdx.x * blockDim.x + threadIdx.x;  // grid sized exactly
    const int i0 = 2 * t;
    const int i1 = i0 + 1;

    const f32x4 xv0 = __builtin_nontemporal_load(&x[i0]);
    const f32x4 xv1 = __builtin_nontemporal_load(&x[i1]);
    const f32x4 lv0 = __builtin_nontemporal_load(&low[i0]);
    const f32x4 lv1 = __builtin_nontemporal_load(&low[i1]);
    const f32x4 hv0 = __builtin_nontemporal_load(&high[i0]);
    const f32x4 hv1 = __builtin_nontemporal_load(&high[i1]);

    f32x4 xr0, lr0, hr0, xr1, lr1, hr1;
    relax_vec(xv0, lv0, hv0, xr0, lr0, hr0);
    relax_vec(xv1, lv1, hv1, xr1, lr1, hr1);

    __builtin_nontemporal_store(xr0, &x_out[i0]);
    __builtin_nontemporal_store(xr1, &x_out[i1]);
    __builtin_nontemporal_store(lr0, &low_out[i0]);
    __builtin_nontemporal_store(lr1, &low_out[i1]);
    __builtin_nontemporal_store(hr0, &high_out[i0]);
    __builtin_nontemporal_store(hr1, &high_out[i1]);
}

extern "C" void kernel_launch(void* const* d_in, const int* in_sizes, int n_in,
                              void* d_out, int out_size, void* d_ws, size_t ws_size,
                              hipStream_t stream) {
    const int n = in_sizes[0];          // 16777216
    const int n4 = n / 4;               // 4194304 float4 elements
    const int nthreads = n4 / 2;        // 2097152, divisible by 256

    const f32x4* x    = (const f32x4*)d_in[0];
    const f32x4* low  = (const f32x4*)d_in[1];
    const f32x4* high = (const f32x4*)d_in[2];

    float* out = (float*)d_out;
    f32x4* x_out    = (f32x4*)(out);
    f32x4* low_out  = (f32x4*)(out + (size_t)n);
    f32x4* high_out = (f32x4*)(out + 2 * (size_t)n);

    const int block = 256;
    const int grid = nthreads / block;  // 8192 blocks, exact map

    abstract_relu_kernel<<<grid, block, 0, stream>>>(x, low, high,
                                                     x_out, low_out, high_out);
}

// Round 6
// 74.947 us; speedup vs baseline: 1.0799x; 1.0799x over previous
//
#include <hip/hip_runtime.h>

// AbstractRelu (DeepPoly ReLU relaxation), elementwise over N=16M fp32.
// Outputs concatenated: [x_out | low_out | high_out], each N floats.
// Memory-bound: 192 MiB in + 192 MiB out, touched once.
// BEST STRUCTURE (round 3, 72.15us = 5.58 TB/s, 89% of measured copy ceiling):
// exact-map, ONE float4 triple per thread, no loop. Latency hidden by TLP
// (fresh waves replace retired ones). Nontemporal everywhere (no reuse,
// footprint > L3). Unrolling (2-way or 4-way, strided or adjacent) REGRESSED
// — do not re-add per-thread work.

#define EPS 1e-7f

typedef float f32x4 __attribute__((ext_vector_type(4)));

__device__ __forceinline__ void relax_one(float X, float L, float H,
                                          float& xo, float& lo, float& ho) {
    xo = fmaxf(X, 0.0f);

    const bool crossing = (L < 0.0f) & (H > 0.0f);
    const bool dead = (H <= 0.0f);

    // Match reference exactly: denom = crossing ? (H-L) : 1.0
    // ub_slope uses denom+EPS, ub_int uses bare denom.
    const float denom = crossing ? (H - L) : 1.0f;
    const float ub_slope = H / (denom + EPS);
    const float ub_int = -(L * H) / denom;
    const float high_cross = ub_slope * H + ub_int;
    // LAMDA = 0 -> low_cross = 0

    ho = crossing ? high_cross : (dead ? 0.0f : H);
    lo = crossing ? 0.0f : (dead ? 0.0f : L);
}

__device__ __forceinline__ void relax_vec(const f32x4& xv, const f32x4& lv,
                                          const f32x4& hv, f32x4& xr,
                                          f32x4& lr, f32x4& hr) {
    float a, b, c;
    relax_one(xv.x, lv.x, hv.x, a, b, c); xr.x = a; lr.x = b; hr.x = c;
    relax_one(xv.y, lv.y, hv.y, a, b, c); xr.y = a; lr.y = b; hr.y = c;
    relax_one(xv.z, lv.z, hv.z, a, b, c); xr.z = a; lr.z = b; hr.z = c;
    relax_one(xv.w, lv.w, hv.w, a, b, c); xr.w = a; lr.w = b; hr.w = c;
}

__global__ void __launch_bounds__(256)
abstract_relu_kernel(const f32x4* __restrict__ x,
                     const f32x4* __restrict__ low,
                     const f32x4* __restrict__ high,
                     f32x4* __restrict__ x_out,
                     f32x4* __restrict__ low_out,
                     f32x4* __restrict__ high_out) {
    const int i = blockIdx.x * blockDim.x + threadIdx.x;  // grid sized exactly

    const f32x4 xv = __builtin_nontemporal_load(&x[i]);
    const f32x4 lv = __builtin_nontemporal_load(&low[i]);
    const f32x4 hv = __builtin_nontemporal_load(&high[i]);

    f32x4 xr, lr, hr;
    relax_vec(xv, lv, hv, xr, lr, hr);

    __builtin_nontemporal_store(xr, &x_out[i]);
    __builtin_nontemporal_store(lr, &low_out[i]);
    __builtin_nontemporal_store(hr, &high_out[i]);
}

extern "C" void kernel_launch(void* const* d_in, const int* in_sizes, int n_in,
                              void* d_out, int out_size, void* d_ws, size_t ws_size,
                              hipStream_t stream) {
    const int n = in_sizes[0];          // 16777216
    const int n4 = n / 4;               // 4194304, divisible by 256

    const f32x4* x    = (const f32x4*)d_in[0];
    const f32x4* low  = (const f32x4*)d_in[1];
    const f32x4* high = (const f32x4*)d_in[2];

    float* out = (float*)d_out;
    f32x4* x_out    = (f32x4*)(out);
    f32x4* low_out  = (f32x4*)(out + (size_t)n);
    f32x4* high_out = (f32x4*)(out + 2 * (size_t)n);

    const int block = 256;
    const int grid = n4 / block;        // 16384 blocks, exact map

    abstract_relu_kernel<<<grid, block, 0, stream>>>(x, low, high,
                                                     x_out, low_out, high_out);
}